// Round 1
// baseline (383.859 us; speedup 1.0000x reference)
//
#include <hip/hip_runtime.h>
#include <hip/hip_bf16.h>

// EdgeDecoder: out[e] = relu(concat(zu[row[e]], zr[col[e]]) @ W1 + b1) @ W2 + b2
// Strategy: gather-GEMM on v_mfma_f32_32x32x16_bf16.
//   - W1 (256x128 fp32) -> bf16, pre-swizzled into 64 KB LDS in B-fragment
//     order (one ds_read_b128 per fragment). Staged once per block, coalesced.
//   - Each wave: 64 edges/sweep (2 M-tiles of 32). kc-outer(16) / nt-inner(4):
//     128 MFMA + 64 ds_read_b128 + 64 gathered global dwordx4 per sweep.
//   - A-fragment layout (verified m120 analog): A[m=lane&31][k=(lane>>5)*8+j],
//     loaded directly from the gathered fp32 row (32B aligned) + cvt to bf16.
//   - C/D layout (verified m74/m101): col=lane&31, row=(reg&3)+8*(reg>>2)+4*(lane>>5).
//   - Fused epilogue: +b1, relu, *W2, shfl_xor butterfly over the 32-lane
//     column group, +b2, store. h[E,128] never materialized.

#define HDIM 128

typedef __attribute__((ext_vector_type(8))) __bf16 bf16x8;
typedef __attribute__((ext_vector_type(16))) float f32x16;

static __device__ __forceinline__ unsigned short bf16_bits(float x) {
  return __builtin_bit_cast(unsigned short, static_cast<__bf16>(x));
}

static __device__ __forceinline__ bf16x8 cvt8(float4 a, float4 b) {
  bf16x8 r;
  r[0] = static_cast<__bf16>(a.x);
  r[1] = static_cast<__bf16>(a.y);
  r[2] = static_cast<__bf16>(a.z);
  r[3] = static_cast<__bf16>(a.w);
  r[4] = static_cast<__bf16>(b.x);
  r[5] = static_cast<__bf16>(b.y);
  r[6] = static_cast<__bf16>(b.z);
  r[7] = static_cast<__bf16>(b.w);
  return r;
}

__global__ __launch_bounds__(256, 2) void edge_decoder_mfma(
    const float* __restrict__ zu, const float* __restrict__ zr,
    const int* __restrict__ eidx, const float* __restrict__ W1,
    const float* __restrict__ b1, const float* __restrict__ W2,
    const float* __restrict__ b2, float* __restrict__ out, int E) {
  // W1 as bf16 in B-fragment order: Bsw[((kc*4+nt)*64+lane)*8+j]
  //   with k = kc*16 + (lane>>5)*8 + j, n = nt*32 + (lane&31)
  __shared__ unsigned short Bsw[32768];  // 64 KB

  const int tid = threadIdx.x;
  {
    // Coalesced staging: thread (tid) reads W1[k][n], n = tid&127, two k's/iter.
    const int n = tid & 127;
    const int kh = tid >> 7;
    const int nt = n >> 5;
    const int nl = n & 31;
#pragma unroll 8
    for (int it = 0; it < 128; ++it) {
      const int k = 2 * it + kh;
      const float w = W1[k * HDIM + n];
      const int kc = k >> 4;
      const int q = (k >> 3) & 1;
      const int j = k & 7;
      const int ln = (q << 5) | nl;
      Bsw[((((kc << 2) + nt) << 6) | ln) * 8 + j] = bf16_bits(w);
    }
  }
  __syncthreads();

  const int lane = tid & 63;
  const int wid = tid >> 6;
  const int m = lane & 31;    // edge row within 32-tile
  const int half = lane >> 5; // k-half selector for A, row-offset for C/D
  const int nsweep = E >> 6;  // 64 edges per sweep (E = 1e6, divisible)
  const int wstride = gridDim.x * 4;

  // Per-lane epilogue constants: columns nt*32 + m
  float b1v[4], w2v[4];
#pragma unroll
  for (int nt = 0; nt < 4; ++nt) {
    b1v[nt] = b1[nt * 32 + m];
    w2v[nt] = W2[nt * 32 + m];
  }
  const float b2v = b2[0];
  const int koff = half * 8;  // element offset within 16-wide k-chunk

  for (int s = blockIdx.x * 4 + wid; s < nsweep; s += wstride) {
    const int e0 = s << 6;
    const int eA = e0 + m;       // M-tile 0
    const int eB = e0 + 32 + m;  // M-tile 1
    const float* puA = zu + (size_t)eidx[eA] * HDIM;
    const float* prA = zr + (size_t)eidx[E + eA] * HDIM;
    const float* puB = zu + (size_t)eidx[eB] * HDIM;
    const float* prB = zr + (size_t)eidx[E + eB] * HDIM;

    f32x16 acc[2][4];
#pragma unroll
    for (int mt = 0; mt < 2; ++mt)
#pragma unroll
      for (int nt = 0; nt < 4; ++nt) acc[mt][nt] = (f32x16)0.0f;

#pragma unroll
    for (int kc = 0; kc < 16; ++kc) {
      // kc 0..7 -> z_user half (k_global = kc*16+...), kc 8..15 -> z_recipe half
      const float* srcA = (kc < 8) ? (puA + kc * 16 + koff) : (prA + (kc - 8) * 16 + koff);
      const float* srcB = (kc < 8) ? (puB + kc * 16 + koff) : (prB + (kc - 8) * 16 + koff);
      const float4* sa = (const float4*)srcA;
      const float4* sb = (const float4*)srcB;
      const bf16x8 a0 = cvt8(sa[0], sa[1]);
      const bf16x8 a1 = cvt8(sb[0], sb[1]);
#pragma unroll
      for (int nt = 0; nt < 4; ++nt) {
        const uint4* bp =
            (const uint4*)(Bsw + ((((kc << 2) + nt) << 6) | lane) * 8);
        const bf16x8 bfr = __builtin_bit_cast(bf16x8, *bp);
        acc[0][nt] = __builtin_amdgcn_mfma_f32_32x32x16_bf16(a0, bfr, acc[0][nt], 0, 0, 0);
        acc[1][nt] = __builtin_amdgcn_mfma_f32_32x32x16_bf16(a1, bfr, acc[1][nt], 0, 0, 0);
      }
    }

    // Epilogue: h = relu(acc + b1); p[reg] = sum_nt h * W2  (per-lane partial
    // over its 4 columns), then butterfly-sum over the 32-lane column group.
    float p0[16], p1[16];
#pragma unroll
    for (int r = 0; r < 16; ++r) {
      p0[r] = 0.f;
      p1[r] = 0.f;
    }
#pragma unroll
    for (int nt = 0; nt < 4; ++nt) {
#pragma unroll
      for (int r = 0; r < 16; ++r) {
        float h0 = fmaxf(acc[0][nt][r] + b1v[nt], 0.f);
        float h1 = fmaxf(acc[1][nt][r] + b1v[nt], 0.f);
        p0[r] = fmaf(h0, w2v[nt], p0[r]);
        p1[r] = fmaf(h1, w2v[nt], p1[r]);
      }
    }
#pragma unroll
    for (int st = 1; st <= 16; st <<= 1) {
#pragma unroll
      for (int r = 0; r < 16; ++r) {
        p0[r] += __shfl_xor(p0[r], st);
        p1[r] += __shfl_xor(p1[r], st);
      }
    }
    // Writer mapping: lane -> (mt, reg). reg sel = lane&15, mt = (lane>>4)&1.
    // row = (sel&3) + 8*(sel>>2) + 4*half  (C/D layout).
    const int sel = lane & 15;
    const int mtw = (lane >> 4) & 1;
    float val = 0.f;
#pragma unroll
    for (int r = 0; r < 16; ++r) {
      const float cand = mtw ? p1[r] : p0[r];
      val = (sel == r) ? cand : val;
    }
    const int mrow = (sel & 3) + ((sel >> 2) << 3) + (half << 2);
    out[e0 + (mtw << 5) + mrow] = val + b2v;
  }
}

extern "C" void kernel_launch(void* const* d_in, const int* in_sizes, int n_in,
                              void* d_out, int out_size, void* d_ws,
                              size_t ws_size, hipStream_t stream) {
  const float* zu = (const float*)d_in[0];
  const float* zr = (const float*)d_in[1];
  const int* eidx = (const int*)d_in[2];
  const float* W1 = (const float*)d_in[3];
  const float* b1 = (const float*)d_in[4];
  const float* W2 = (const float*)d_in[5];
  const float* b2 = (const float*)d_in[6];
  float* out = (float*)d_out;
  const int E = in_sizes[2] / 2;  // 1,000,000

  // 512 blocks x 256 threads: 2 blocks/CU (64 KB LDS each), grid-strided sweeps.
  dim3 grid(512), block(256);
  hipLaunchKernelGGL(edge_decoder_mfma, grid, block, 0, stream, zu, zr, eidx,
                     W1, b1, W2, b2, out, E);
}